// Round 6
// baseline (267.135 us; speedup 1.0000x reference)
//
#include <hip/hip_runtime.h>
#include <math.h>

#define HH 2048
#define WW 2048
#define NROWS (11 * HH)     // 22528 rows total
#define NB 256              // staging block size (4 waves)
#define SGRID 1024          // staging grid: 4096 waves, 5.5 rows/wave
#define NBC 1024            // chain block size (16 waves)
#define NWC (NBC / 64)

// ---------- wave reductions (no LDS, no barriers) ----------
__device__ __forceinline__ float wave_fmax(float v) {
#pragma unroll
  for (int m = 1; m < 64; m <<= 1) v = fmaxf(v, __shfl_xor(v, m, 64));
  return v;
}
__device__ __forceinline__ float wave_fsum(float v) {
#pragma unroll
  for (int m = 1; m < 64; m <<= 1) v += __shfl_xor(v, m, 64);
  return v;
}

// ---------- per-row softmax partial, ONE wave, zero barriers ----------
// Returns (M, z, sx): M = max(100*v), z = sum(exp(100*v-M)), sx = sum(exp*col).
// NOTE: keep bit-identical across rounds (R5 verified absmax 0.0).
__device__ float4 wave_row_partial(const float* __restrict__ rowp) {
  const int lane = threadIdx.x & 63;
  const float4* r4 = (const float4*)rowp;
  float d[32];
  float m = -INFINITY;
#pragma unroll
  for (int p = 0; p < 8; ++p) {
    float4 v = r4[lane + 64 * p];
    d[4 * p + 0] = v.x * 100.0f;  // BETA
    d[4 * p + 1] = v.y * 100.0f;
    d[4 * p + 2] = v.z * 100.0f;
    d[4 * p + 3] = v.w * 100.0f;
    m = fmaxf(m, fmaxf(fmaxf(d[4 * p], d[4 * p + 1]), fmaxf(d[4 * p + 2], d[4 * p + 3])));
  }
  float M = wave_fmax(m);
  float z = 0.0f, sx = 0.0f;
#pragma unroll
  for (int p = 0; p < 8; ++p) {
    float c0 = (float)(4 * (lane + 64 * p));
#pragma unroll
    for (int k = 0; k < 4; ++k) {
      float e = expf(d[4 * p + k] - M);
      z += e;
      sx += e * (c0 + (float)k);
    }
  }
  z = wave_fsum(z);
  sx = wave_fsum(sx);
  return make_float4(M, z, sx, 0.0f);
}

// ---------- chain-block (NBC threads) reductions ----------
__device__ float blockc_fmax(float v) {
  __shared__ float s[NWC];
  v = wave_fmax(v);
  __syncthreads();                        // WAR guard across calls
  if ((threadIdx.x & 63) == 0) s[threadIdx.x >> 6] = v;
  __syncthreads();
  float r = s[0];
#pragma unroll
  for (int k = 1; k < NWC; ++k) r = fmaxf(r, s[k]);
  return r;
}
__device__ void blockc_fsum3(float& a, float& b, float& c) {
  __shared__ float sa[NWC], sb[NWC], sc[NWC];
  a = wave_fsum(a); b = wave_fsum(b); c = wave_fsum(c);
  __syncthreads();                        // WAR guard across calls
  if ((threadIdx.x & 63) == 0) {
    int w = threadIdx.x >> 6;
    sa[w] = a; sb[w] = b; sc[w] = c;
  }
  __syncthreads();
  float ra = 0.0f, rb = 0.0f, rc = 0.0f;
#pragma unroll
  for (int k = 0; k < NWC; ++k) { ra += sa[k]; rb += sb[k]; rc += sc[k]; }
  a = ra; b = rb; c = rc;
}

// Merge per-row partials arr[r], r in [s,e] (sy weight = r). Broadcast result.
__device__ void merge_partials(const float4* __restrict__ arr, int s, int e,
                               float& M, float& Z, float& SX, float& SY) {
  float m = -INFINITY;
  for (int r = s + (int)threadIdx.x; r <= e; r += NBC) m = fmaxf(m, arr[r].x);
  M = blockc_fmax(m);
  float z = 0.0f, sx = 0.0f, sy = 0.0f;
  for (int r = s + (int)threadIdx.x; r <= e; r += NBC) {
    float4 p = arr[r];                    // L2-hot second read
    float w = expf(p.x - M);
    z  += w * p.y;
    sx += w * p.z;
    sy += w * p.y * (float)r;
  }
  blockc_fsum3(z, sx, sy);
  Z = z; SX = sx; SY = sy;
}

// Analytic out-of-band complement (masked elements are exactly 0), then divide.
__device__ void finalize2(float M, float Z, float SX, float SY, int s, int e,
                          bool valid, float& ax, float& ay) {
  int nin = valid ? (e - s + 1) : 0;
  int nout = HH - nin;
  if (nout > 0) {
    float M2 = fmaxf(M, 0.0f);
    float wi = (M == M2) ? 1.0f : expf(M - M2);   // M=-inf -> 0
    float wo = (M2 == 0.0f) ? 1.0f : expf(-M2);   // underflows to 0 for typical M
    Z *= wi; SX *= wi; SY *= wi;
    float nout_e = (float)nout * (float)WW;                                  // exact
    float sox = (float)nout * 2096128.0f;                                    // nout*W(W-1)/2
    float sinr = valid ? (float)(((long)(s + e) * (e - s + 1)) / 2) : 0.0f;  // exact
    float soy = (2096128.0f - sinr) * 2048.0f;                               // exact
    Z  += wo * nout_e;
    SX += wo * sox;
    SY += wo * soy;
  }
  ax = SX / Z;
  ay = SY / Z;
}

// ws layout: [0..511] header (unused), F at ws+512: NROWS x float4 row partials.

// Eager staging: per-wave rows, grid-stride, zero barriers. 184 MB streaming.
__global__ __launch_bounds__(NB) void k_rows_all(const float* __restrict__ heat,
                                                 float* ws) {
  float4* F = (float4*)(ws + 512);
  const int nw = SGRID * (NB / 64);
  for (int r = blockIdx.x * (NB / 64) + ((int)threadIdx.x >> 6); r < NROWS; r += nw) {
    float4 t = wave_row_partial(heat + (size_t)r * WW);
    if ((threadIdx.x & 63) == 0) F[r] = t;
  }
}

// Single block (16 waves) walks the entire sequential chain over 360 KB of partials.
__global__ __launch_bounds__(NBC) void k_chain(float* ws, float* __restrict__ out) {
  const float4* F = (const float4*)(ws + 512);
  float st[22];
  float M, Z, SX, SY, ax, ay;

  merge_partials(F + 9 * HH, 0, HH - 1, M, Z, SX, SY);
  finalize2(M, Z, SX, SY, 0, HH - 1, true, ax, ay);
  st[18] = ax; st[19] = ay;                               // out[9]
  merge_partials(F + 10 * HH, 0, HH - 1, M, Z, SX, SY);
  finalize2(M, Z, SX, SY, 0, HH - 1, true, ax, ay);
  st[20] = ax; st[21] = ay;                               // out[10]

  float dis = st[21] - st[19], dsum = 0.0f, dnum = 0.0f;

  for (int i = 8; i >= 0; --i) {
    float y1 = st[2 * (i + 1) + 1];
    float y2 = st[2 * (i + 2) + 1];
    float last_y = floorf(y1);
    float tmp = ceilf(y2 - y1);
    bool cond = fabsf(tmp - dis) > 0.35f * dis;
    if (cond) { dsum += tmp; dnum += 1.0f; dis = dsum / fmaxf(dnum, 1.0f); }
    float start_raw = last_y - 1.8f * dis;
    float end_f   = rintf(start_raw + 1.8f * dis);   // jnp.round = rint (half-to-even)
    float start_f = rintf(start_raw);
    int s = (int)fmaxf(start_f, 0.0f);
    int e = (int)fminf(end_f, (float)(HH - 1));
    bool valid = (s <= e) && (end_f >= 0.0f) && (start_f <= (float)(HH - 1));
    M = -INFINITY; Z = 0.0f; SX = 0.0f; SY = 0.0f;
    if (valid) merge_partials(F + (size_t)i * HH, s, e, M, Z, SX, SY);  // uniform branch
    finalize2(M, Z, SX, SY, s, e, valid, ax, ay);
    st[2 * i] = ax; st[2 * i + 1] = ay;
  }

  if (threadIdx.x < 22) out[threadIdx.x] = st[threadIdx.x];
}

extern "C" void kernel_launch(void* const* d_in, const int* in_sizes, int n_in,
                              void* d_out, int out_size, void* d_ws, size_t ws_size,
                              hipStream_t stream) {
  const float* heat = (const float*)d_in[0];
  float* out = (float*)d_out;
  float* ws = (float*)d_ws;
  hipLaunchKernelGGL(k_rows_all, dim3(SGRID), dim3(NB), 0, stream, heat, ws);
  hipLaunchKernelGGL(k_chain, dim3(1), dim3(NBC), 0, stream, ws, out);
}